// Round 1
// 1984.529 us; speedup vs baseline: 1.7637x; 1.7637x over previous
//
#include <hip/hip_runtime.h>

// EigenvalueNet: loss = mean((R@S - w*R)^2), R,S f32[8192,8192], w f32[8192,1]
// V2 strategy: pre-convert R->bf16 (row-major) and S->bf16 TRANSPOSED [n][k]
// into workspace (memory-bound passes), then run an m97-structure bf16 GEMM:
// 128x128 tile, BK=32, global_load_lds width=16 staging (no VALU conversion,
// no LDS write instructions in the hot loop), fused resid^2 epilogue.
// Falls back to the previous fused kernel if workspace < 256MB.

#define U_DIM 8192
#define I_DIM 8192
#define K_DIM 8192

#define BM 128
#define BN 128
#define BK 32

typedef __attribute__((ext_vector_type(8))) short bf16x8;
typedef __attribute__((ext_vector_type(4))) float f32x4;

__device__ __forceinline__ unsigned int bf16_rne_bits(float x) {
    // f32 -> bf16 round-nearest-even, result in low 16 bits (normal inputs)
    unsigned int u = __builtin_bit_cast(unsigned int, x);
    return (u + 0x7fffu + ((u >> 16) & 1u)) >> 16;
}

__device__ __forceinline__ unsigned int pk2(float x, float y) {
    return bf16_rne_bits(x) | (bf16_rne_bits(y) << 16);
}

__device__ __forceinline__ void gload16(const void* g, void* l) {
    // 16B per lane, LDS dest = wave-uniform base + lane*16 (HW rule)
    __builtin_amdgcn_global_load_lds(
        (const __attribute__((address_space(1))) unsigned int*)g,
        (__attribute__((address_space(3))) unsigned int*)l, 16, 0, 0);
}

__global__ void zero_out_kernel(float* out) { out[0] = 0.0f; }

// ---- pass 1a: R f32 -> bf16, same row-major layout ----
__global__ __launch_bounds__(256) void convR_kernel(
    const float* __restrict__ R, unsigned short* __restrict__ Rb)
{
    const size_t idx = (size_t)blockIdx.x * 256 + threadIdx.x; // 8 elems/thread
    const float4 a = *(const float4*)(R + idx * 8);
    const float4 b = *(const float4*)(R + idx * 8 + 4);
    uint4 w;
    w.x = pk2(a.x, a.y); w.y = pk2(a.z, a.w);
    w.z = pk2(b.x, b.y); w.w = pk2(b.z, b.w);
    *(uint4*)(Rb + idx * 8) = w;
}

// ---- pass 1b: S f32 [k][n] -> bf16 TRANSPOSED [n][k] via 64x64 LDS tile ----
__global__ __launch_bounds__(256) void convS_kernel(
    const float* __restrict__ S, unsigned short* __restrict__ STb)
{
    __shared__ unsigned short T[64][72];   // [n][k], 144B rows (16B aligned)
    const int n0 = (blockIdx.x & 127) * 64;
    const int k0 = (blockIdx.x >> 7) * 64;
    const int t  = threadIdx.x;
    const int c4 = (t & 15) * 4;   // n-offset within tile
    const int r  = t >> 4;         // k-offset base (0..15)
    #pragma unroll
    for (int p = 0; p < 4; p++) {
        const int kk = r + p * 16;
        const float4 v = *(const float4*)(S + (size_t)(k0 + kk) * I_DIM + n0 + c4);
        T[c4 + 0][kk] = (unsigned short)bf16_rne_bits(v.x);
        T[c4 + 1][kk] = (unsigned short)bf16_rne_bits(v.y);
        T[c4 + 2][kk] = (unsigned short)bf16_rne_bits(v.z);
        T[c4 + 3][kk] = (unsigned short)bf16_rne_bits(v.w);
    }
    __syncthreads();
    #pragma unroll
    for (int c = t; c < 512; c += 256) {
        const int nn = c >> 3;
        const int ch = c & 7;
        const uint4 w = *(const uint4*)&T[nn][ch * 8];
        *(uint4*)(STb + (size_t)(n0 + nn) * K_DIM + k0 + ch * 8) = w;
    }
}

// ---- pass 2: m97-structure bf16 GEMM with fused loss epilogue ----
// Ab: [U][K] bf16 row-major; Bb: [N][K] bf16 (= S^T)
__global__ __launch_bounds__(256) void gemm_loss_kernel(
    const unsigned short* __restrict__ Ab, const unsigned short* __restrict__ Bb,
    const float* __restrict__ R, const float* __restrict__ W,
    float* __restrict__ out)
{
    __shared__ unsigned short As[BM * BK];   // [m][k] linear (gload_lds dest)
    __shared__ unsigned short Bs[BN * BK];   // [n][k] linear
    __shared__ float wavesum[4];

    const int tid  = threadIdx.x;
    const int lane = tid & 63;
    const int wave = tid >> 6;
    const int wm   = wave >> 1;   // wave row (0..1)
    const int wn   = wave & 1;    // wave col (0..1)
    const int q    = lane >> 4;   // quad 0..3
    const int l16  = lane & 15;

    // 8x8 supertile swizzle: 64 consecutive blocks share 8 A-panels + 8
    // B-panels for L2/LLC reuse.
    const int bid = blockIdx.x;
    const int sq  = bid >> 6;
    const int w64 = bid & 63;
    const int br  = (sq >> 3) * 8 + (w64 >> 3);
    const int bc  = (sq & 7) * 8 + (w64 & 7);
    const int row0 = br * BM;
    const int col0 = bc * BN;

    // Staging: per wave 2 gload_lds per operand; each instr = 16 rows x 64B.
    // Lane i covers row (base + i>>2), bytes (i&3)*16 of the 64B k-chunk.
    const int srow = lane >> 2;
    const int selt = (lane & 3) * 8;   // bf16 elems
    const unsigned short* gA = Ab + (size_t)(row0 + wave * 32 + srow) * K_DIM + selt;
    const unsigned short* gB = Bb + (size_t)(col0 + wave * 32 + srow) * K_DIM + selt;
    unsigned short* ldsA0 = &As[(wave * 32) * BK];
    unsigned short* ldsA1 = &As[(wave * 32 + 16) * BK];
    unsigned short* ldsB0 = &Bs[(wave * 32) * BK];
    unsigned short* ldsB1 = &Bs[(wave * 32 + 16) * BK];

    f32x4 acc[4][4];
    #pragma unroll
    for (int i = 0; i < 4; i++)
        #pragma unroll
        for (int j = 0; j < 4; j++)
            acc[i][j] = (f32x4){0.f, 0.f, 0.f, 0.f};

    for (int k0 = 0; k0 < K_DIM; k0 += BK) {
        __syncthreads();   // prior iteration's LDS reads complete
        gload16(gA,                        ldsA0);
        gload16(gA + (size_t)16 * K_DIM,   ldsA1);
        gload16(gB,                        ldsB0);
        gload16(gB + (size_t)16 * K_DIM,   ldsB1);
        gA += BK;
        gB += BK;
        __syncthreads();   // compiler drains vmcnt(0) before barrier -> tile ready

        bf16x8 af[4], bfr[4];
        #pragma unroll
        for (int i = 0; i < 4; i++)
            af[i] = *(const bf16x8*)&As[(wm * 64 + i * 16 + l16) * BK + q * 8];
        #pragma unroll
        for (int j = 0; j < 4; j++)
            bfr[j] = *(const bf16x8*)&Bs[(wn * 64 + j * 16 + l16) * BK + q * 8];
        #pragma unroll
        for (int i = 0; i < 4; i++)
            #pragma unroll
            for (int j = 0; j < 4; j++)
                acc[i][j] = __builtin_amdgcn_mfma_f32_16x16x32_bf16(
                    af[i], bfr[j], acc[i][j], 0, 0, 0);
    }

    // ---- fused epilogue: resid = pred - w*R, accumulate resid^2 ----
    // C/D layout: col = lane&15, row = quad*4 + reg (m89/m91-verified)
    float lsum = 0.0f;
    #pragma unroll
    for (int i = 0; i < 4; i++) {
        #pragma unroll
        for (int r = 0; r < 4; r++) {
            const int grow = row0 + wm * 64 + i * 16 + q * 4 + r;
            const float wv = W[grow];
            const float* Rrow = R + (size_t)grow * I_DIM + col0 + wn * 64 + l16;
            #pragma unroll
            for (int j = 0; j < 4; j++) {
                const float resid = acc[i][j][r] - wv * Rrow[j * 16];
                lsum += resid * resid;
            }
        }
    }

    #pragma unroll
    for (int off = 32; off > 0; off >>= 1)
        lsum += __shfl_down(lsum, off);
    if (lane == 0) wavesum[wave] = lsum;
    __syncthreads();
    if (tid == 0) {
        const float bs = wavesum[0] + wavesum[1] + wavesum[2] + wavesum[3];
        atomicAdd(out, bs * (1.0f / ((float)U_DIM * (float)I_DIM)));
    }
}

// ---- fallback: previous fused kernel (reg-staged conversion in-loop) ----
#define LDA 40
#define LDB 40

__global__ __launch_bounds__(256) void fused_loss_kernel(
    const float* __restrict__ R, const float* __restrict__ S,
    const float* __restrict__ W, float* __restrict__ out)
{
    __shared__ unsigned short As[BM * LDA];
    __shared__ unsigned short Bs[BN * LDB];
    __shared__ float wavesum[4];

    const int tid  = threadIdx.x;
    const int lane = tid & 63;
    const int wave = tid >> 6;
    const int wm   = wave >> 1;
    const int wn   = wave & 1;
    const int q    = lane >> 4;
    const int l16  = lane & 15;

    const int bid = blockIdx.x;
    const int sq  = bid >> 6;
    const int w64 = bid & 63;
    const int br  = (sq >> 3) * 8 + (w64 >> 3);
    const int bc  = (sq & 7) * 8 + (w64 & 7);
    const int row0 = br * BM;
    const int col0 = bc * BN;

    const int ra = tid >> 2;
    const int ca = (tid & 3) * 8;
    const float* gA = R + (size_t)(row0 + ra) * (size_t)K_DIM + ca;

    const int kb2 = (tid & 15) * 2;
    const int nb  = (tid >> 4) * 8;
    const float* gB = S + (size_t)kb2 * (size_t)I_DIM + col0 + nb;

    f32x4 acc[4][4];
    #pragma unroll
    for (int i = 0; i < 4; i++)
        #pragma unroll
        for (int j = 0; j < 4; j++)
            acc[i][j] = (f32x4){0.f, 0.f, 0.f, 0.f};

    for (int k0 = 0; k0 < K_DIM; k0 += BK) {
        const float4 a0 = *(const float4*)(gA);
        const float4 a1 = *(const float4*)(gA + 4);
        const float4 a2 = *(const float4*)(gA + (size_t)64 * K_DIM);
        const float4 a3 = *(const float4*)(gA + (size_t)64 * K_DIM + 4);
        const float4 b0 = *(const float4*)(gB);
        const float4 b1 = *(const float4*)(gB + 4);
        const float4 b2 = *(const float4*)(gB + I_DIM);
        const float4 b3 = *(const float4*)(gB + I_DIM + 4);
        gA += BK;
        gB += (size_t)BK * I_DIM;

        __syncthreads();

        uint4 wa0; wa0.x = pk2(a0.x, a0.y); wa0.y = pk2(a0.z, a0.w);
                   wa0.z = pk2(a1.x, a1.y); wa0.w = pk2(a1.z, a1.w);
        *(uint4*)&As[ra * LDA + ca] = wa0;
        uint4 wa1; wa1.x = pk2(a2.x, a2.y); wa1.y = pk2(a2.z, a2.w);
                   wa1.z = pk2(a3.x, a3.y); wa1.w = pk2(a3.z, a3.w);
        *(uint4*)&As[(ra + 64) * LDA + ca] = wa1;

        float r0[8] = {b0.x, b0.y, b0.z, b0.w, b1.x, b1.y, b1.z, b1.w};
        float r1[8] = {b2.x, b2.y, b2.z, b2.w, b3.x, b3.y, b3.z, b3.w};
        #pragma unroll
        for (int e = 0; e < 8; e++) {
            *(unsigned int*)&Bs[(nb + e) * LDB + kb2] = pk2(r0[e], r1[e]);
        }
        __syncthreads();

        bf16x8 af[4], bfr[4];
        #pragma unroll
        for (int i = 0; i < 4; i++)
            af[i] = *(const bf16x8*)&As[(wm * 64 + i * 16 + l16) * LDA + q * 8];
        #pragma unroll
        for (int j = 0; j < 4; j++)
            bfr[j] = *(const bf16x8*)&Bs[(wn * 64 + j * 16 + l16) * LDB + q * 8];
        #pragma unroll
        for (int i = 0; i < 4; i++)
            #pragma unroll
            for (int j = 0; j < 4; j++)
                acc[i][j] = __builtin_amdgcn_mfma_f32_16x16x32_bf16(
                    af[i], bfr[j], acc[i][j], 0, 0, 0);
    }

    float lsum = 0.0f;
    #pragma unroll
    for (int i = 0; i < 4; i++) {
        #pragma unroll
        for (int r = 0; r < 4; r++) {
            const int grow = row0 + wm * 64 + i * 16 + q * 4 + r;
            const float wv = W[grow];
            const float* Rrow = R + (size_t)grow * I_DIM + col0 + wn * 64 + l16;
            #pragma unroll
            for (int j = 0; j < 4; j++) {
                const float resid = acc[i][j][r] - wv * Rrow[j * 16];
                lsum += resid * resid;
            }
        }
    }

    #pragma unroll
    for (int off = 32; off > 0; off >>= 1)
        lsum += __shfl_down(lsum, off);
    if (lane == 0) wavesum[wave] = lsum;
    __syncthreads();
    if (tid == 0) {
        const float bs = wavesum[0] + wavesum[1] + wavesum[2] + wavesum[3];
        atomicAdd(out, bs * (1.0f / ((float)U_DIM * (float)I_DIM)));
    }
}

extern "C" void kernel_launch(void* const* d_in, const int* in_sizes, int n_in,
                              void* d_out, int out_size, void* d_ws, size_t ws_size,
                              hipStream_t stream) {
    const float* R = (const float*)d_in[0];
    const float* S = (const float*)d_in[1];
    const float* W = (const float*)d_in[2];
    float* out = (float*)d_out;

    zero_out_kernel<<<dim3(1), dim3(1), 0, stream>>>(out);

    const size_t need = (size_t)U_DIM * K_DIM * 2 + (size_t)I_DIM * K_DIM * 2; // 256MB
    if (ws_size >= need) {
        unsigned short* Rb  = (unsigned short*)d_ws;
        unsigned short* STb = Rb + (size_t)U_DIM * K_DIM;
        convR_kernel<<<dim3((U_DIM / 1) * (K_DIM / 8) / 256), dim3(256), 0, stream>>>(R, Rb);
        convS_kernel<<<dim3((K_DIM / 64) * (I_DIM / 64)), dim3(256), 0, stream>>>(S, STb);
        gemm_loss_kernel<<<dim3((U_DIM / BM) * (I_DIM / BN)), dim3(256), 0, stream>>>(
            Rb, STb, R, W, out);
    } else {
        fused_loss_kernel<<<dim3((U_DIM / BM) * (I_DIM / BN)), dim3(256), 0, stream>>>(
            R, S, W, out);
    }
}

// Round 2
// 1554.760 us; speedup vs baseline: 2.2513x; 1.2764x over previous
//
#include <hip/hip_runtime.h>

// EigenvalueNet: loss = mean((R@S - w*R)^2), R,S f32[8192,8192], w f32[8192,1]
// V3: pre-convert R->bf16 row-major, S->bf16 transposed [n][k] (workspace),
// then a 256x256-tile 8-phase bf16 GEMM (HK-style schedule in plain HIP):
//   - BK=64, 8 waves (2Mx4N), 512 threads, 128KiB LDS double-buffer
//   - counted vmcnt(6) at phases 4/8 only (loads stay in flight across barriers)
//   - T2 XOR-swizzle (c ^= row&7 on 16B k-chunks) via pre-swizzled global src
//   - setprio(1) around each 16-MFMA quadrant cluster
// Fused resid^2 epilogue + block reduction. Fallback to proven V1 kernel if
// workspace < 256MB.

#define U_DIM 8192
#define I_DIM 8192
#define K_DIM 8192

typedef __attribute__((ext_vector_type(8))) short bf16x8;
typedef __attribute__((ext_vector_type(4))) float f32x4;

__device__ __forceinline__ unsigned int bf16_rne_bits(float x) {
    unsigned int u = __builtin_bit_cast(unsigned int, x);
    return (u + 0x7fffu + ((u >> 16) & 1u)) >> 16;
}

__device__ __forceinline__ unsigned int pk2(float x, float y) {
    return bf16_rne_bits(x) | (bf16_rne_bits(y) << 16);
}

__device__ __forceinline__ void gload16(const void* g, void* l) {
    __builtin_amdgcn_global_load_lds(
        (const __attribute__((address_space(1))) unsigned int*)g,
        (__attribute__((address_space(3))) unsigned int*)l, 16, 0, 0);
}

#define SBAR()  __builtin_amdgcn_s_barrier()
#define LGKM0() asm volatile("s_waitcnt lgkmcnt(0)" ::: "memory")
#define VMC6()  asm volatile("s_waitcnt vmcnt(6)" ::: "memory")
#define PRIO1() __builtin_amdgcn_s_setprio(1)
#define PRIO0() __builtin_amdgcn_s_setprio(0)

__global__ void zero_out_kernel(float* out) { out[0] = 0.0f; }

// ---- pass 1a: R f32 -> bf16, row-major ----
__global__ __launch_bounds__(256) void convR_kernel(
    const float* __restrict__ R, unsigned short* __restrict__ Rb)
{
    const size_t idx = (size_t)blockIdx.x * 256 + threadIdx.x;
    const float4 a = *(const float4*)(R + idx * 8);
    const float4 b = *(const float4*)(R + idx * 8 + 4);
    uint4 w;
    w.x = pk2(a.x, a.y); w.y = pk2(a.z, a.w);
    w.z = pk2(b.x, b.y); w.w = pk2(b.z, b.w);
    *(uint4*)(Rb + idx * 8) = w;
}

// ---- pass 1b: S f32 [k][n] -> bf16 transposed [n][k] ----
__global__ __launch_bounds__(256) void convS_kernel(
    const float* __restrict__ S, unsigned short* __restrict__ STb)
{
    __shared__ unsigned short T[64][72];
    const int n0 = (blockIdx.x & 127) * 64;
    const int k0 = (blockIdx.x >> 7) * 64;
    const int t  = threadIdx.x;
    const int c4 = (t & 15) * 4;
    const int r  = t >> 4;
    #pragma unroll
    for (int p = 0; p < 4; p++) {
        const int kk = r + p * 16;
        const float4 v = *(const float4*)(S + (size_t)(k0 + kk) * I_DIM + n0 + c4);
        T[c4 + 0][kk] = (unsigned short)bf16_rne_bits(v.x);
        T[c4 + 1][kk] = (unsigned short)bf16_rne_bits(v.y);
        T[c4 + 2][kk] = (unsigned short)bf16_rne_bits(v.z);
        T[c4 + 3][kk] = (unsigned short)bf16_rne_bits(v.w);
    }
    __syncthreads();
    #pragma unroll
    for (int c = t; c < 512; c += 256) {
        const int nn = c >> 3;
        const int ch = c & 7;
        const uint4 w = *(const uint4*)&T[nn][ch * 8];
        *(uint4*)(STb + (size_t)(n0 + nn) * K_DIM + k0 + ch * 8) = w;
    }
}

// ---- pass 2: 256^2 8-phase bf16 GEMM + fused loss ----
// Ab: [U][K] bf16; Bb: [N][K] bf16 (= S^T). LDS tiles 256x64 bf16 per operand,
// double-buffered. Swizzle: 16B slot (row, c) holds logical k-chunk c^(row&7).
__global__ __launch_bounds__(512, 2) void gemm_loss_kernel(
    const unsigned short* __restrict__ Ab, const unsigned short* __restrict__ Bb,
    const float* __restrict__ R, const float* __restrict__ W,
    float* __restrict__ out)
{
    __shared__ unsigned short As[2][256 * 64];   // 64 KiB
    __shared__ unsigned short Bs[2][256 * 64];   // 64 KiB

    const int tid  = threadIdx.x;
    const int lane = tid & 63;
    const int wave = tid >> 6;
    const int wm   = wave >> 2;   // 0..1: M half
    const int wn   = wave & 3;    // 0..3: N slot (cols wn*32 + qn*128)
    const int q    = lane >> 4;
    const int l16  = lane & 15;

    // XCD-bijective swizzle (1024 blocks % 8 == 0) + 8x8 supertile
    const int bid  = blockIdx.x;
    const int wgid = (bid & 7) * 128 + (bid >> 3);
    const int sq   = wgid >> 6;
    const int w64  = wgid & 63;
    const int br   = (sq >> 2) * 8 + (w64 >> 3);
    const int bc   = (sq & 3) * 8 + (w64 & 7);
    const int row0 = br * 256;
    const int col0 = bc * 256;

    // Staging constants: thread covers 16B slot (srow, tid&7) of each 64-row
    // chunk; fetches the logical chunk that belongs there under the swizzle.
    const int srow = tid >> 3;                       // 0..63
    const int csrc = ((tid & 7) ^ (srow & 7)) * 8;   // pre-swizzled k elems
    const unsigned short* gAst = Ab + (size_t)(row0 + srow) * K_DIM + csrc;
    const unsigned short* gBst = Bb + (size_t)(col0 + srow) * K_DIM + csrc;
    unsigned short* As0 = &As[0][0];
    unsigned short* As1 = &As[1][0];
    unsigned short* Bs0 = &Bs[0][0];
    unsigned short* Bs1 = &Bs[1][0];

    // ds_read swizzled chunk offsets (ushort units) for k-steps s=0,1
    const int cv  = l16 & 7;
    const int cA0 = ((0 + q) ^ cv) * 8;
    const int cA1 = ((4 + q) ^ cv) * 8;

// stage one 64-row chunk (1 instr, 512 threads x 16B = 8 KiB)
#define STG(gp, lp, r0, kt) \
    gload16((gp) + (size_t)(r0) * K_DIM + (size_t)(kt) * 64, \
            (lp) + (r0) * 64 + wave * 512)

#define LOAD_A(AC, qm) do { \
    _Pragma("unroll") for (int m = 0; m < 4; m++) { \
        const int rr = (wm * 128 + (qm) * 64 + m * 16 + l16) * 64; \
        afr[m][0] = *(const bf16x8*)&(AC)[rr + cA0]; \
        afr[m][1] = *(const bf16x8*)&(AC)[rr + cA1]; \
    } } while (0)

#define LOAD_B(BC, qn) do { \
    _Pragma("unroll") for (int n = 0; n < 2; n++) { \
        const int rr = (wn * 32 + (qn) * 128 + n * 16 + l16) * 64; \
        bfr[n][0] = *(const bf16x8*)&(BC)[rr + cA0]; \
        bfr[n][1] = *(const bf16x8*)&(BC)[rr + cA1]; \
    } } while (0)

#define MM(qm, qn) do { \
    _Pragma("unroll") for (int m = 0; m < 4; m++) \
    _Pragma("unroll") for (int n = 0; n < 2; n++) { \
        acc[(qm)*4+m][(qn)*2+n] = __builtin_amdgcn_mfma_f32_16x16x32_bf16( \
            afr[m][0], bfr[n][0], acc[(qm)*4+m][(qn)*2+n], 0, 0, 0); \
        acc[(qm)*4+m][(qn)*2+n] = __builtin_amdgcn_mfma_f32_16x16x32_bf16( \
            afr[m][1], bfr[n][1], acc[(qm)*4+m][(qn)*2+n], 0, 0, 0); \
    } } while (0)

    f32x4 acc[8][4];
    #pragma unroll
    for (int i = 0; i < 8; i++)
        #pragma unroll
        for (int j = 0; j < 4; j++)
            acc[i][j] = (f32x4){0.f, 0.f, 0.f, 0.f};

    bf16x8 afr[4][2], bfr[2][2];

    // ---- prologue: tile0 (4 regions) + tile1 (3 regions); B-T1 h0 at P1 ----
    STG(gAst, As0, 0, 0);   STG(gAst, As0, 128, 0);   // A-T0 qm=0 quarters
    STG(gBst, Bs0, 128, 0); STG(gBst, Bs0, 192, 0);   // B-T0 half1
    STG(gAst, As0, 64, 0);  STG(gAst, As0, 192, 0);   // A-T0 qm=1 quarters
    STG(gBst, Bs0, 0, 0);   STG(gBst, Bs0, 64, 0);    // B-T0 half0
    STG(gAst, As1, 0, 1);   STG(gAst, As1, 128, 1);   // A-T1 qm=0
    STG(gBst, Bs1, 128, 1); STG(gBst, Bs1, 192, 1);   // B-T1 half1
    STG(gAst, As1, 64, 1);  STG(gAst, As1, 192, 1);   // A-T1 qm=1
    VMC6();   // oldest 8 (= all of T0) landed; 6 of T1 still in flight
    SBAR();

    #pragma unroll 1
    for (int it = 0; it < 64; it++) {
        const int kO1 = (2 * it + 1) & 127;   // B h0 of odd tile (this iter P5-P8)
        const int kE2 = (2 * it + 2) & 127;   // next even tile -> buf0
        const int kO2 = (2 * it + 3) & 127;   // next odd tile  -> buf1

        // P1: quadrant (0,0) of even tile; stage B-odd h0
        LOAD_A(As0, 0); LOAD_B(Bs0, 0);
        STG(gBst, Bs1, 0, kO1); STG(gBst, Bs1, 64, kO1);
        SBAR(); LGKM0();
        PRIO1(); MM(0, 0); PRIO0();
        SBAR();
        // P2: (0,1); stage A-next-even qm=0 quarters (freed at P1)
        LOAD_B(Bs0, 1);
        STG(gAst, As0, 0, kE2); STG(gAst, As0, 128, kE2);
        SBAR(); LGKM0();
        PRIO1(); MM(0, 1); PRIO0();
        SBAR();
        // P3: (1,1); stage B-next-even h1 (freed at P2)
        LOAD_A(As0, 1);
        STG(gBst, Bs0, 128, kE2); STG(gBst, Bs0, 192, kE2);
        SBAR(); LGKM0();
        PRIO1(); MM(1, 1); PRIO0();
        SBAR();
        // P4: (1,0); stage A-next-even qm=1 quarters (freed at P3); vmcnt(6)
        LOAD_B(Bs0, 0);
        STG(gAst, As0, 64, kE2); STG(gAst, As0, 192, kE2);
        SBAR(); LGKM0();
        PRIO1(); MM(1, 0); PRIO0();
        VMC6();   // odd tile fully landed (through P1's stage)
        SBAR();
        // P5: (0,0) of odd tile; stage B-next-even h0 (freed at P4)
        LOAD_A(As1, 0); LOAD_B(Bs1, 0);
        STG(gBst, Bs0, 0, kE2); STG(gBst, Bs0, 64, kE2);
        SBAR(); LGKM0();
        PRIO1(); MM(0, 0); PRIO0();
        SBAR();
        // P6: (0,1); stage A-next-odd qm=0
        LOAD_B(Bs1, 1);
        STG(gAst, As1, 0, kO2); STG(gAst, As1, 128, kO2);
        SBAR(); LGKM0();
        PRIO1(); MM(0, 1); PRIO0();
        SBAR();
        // P7: (1,1); stage B-next-odd h1
        LOAD_A(As1, 1);
        STG(gBst, Bs1, 128, kO2); STG(gBst, Bs1, 192, kO2);
        SBAR(); LGKM0();
        PRIO1(); MM(1, 1); PRIO0();
        SBAR();
        // P8: (1,0); stage A-next-odd qm=1; vmcnt(6)
        LOAD_B(Bs1, 0);
        STG(gAst, As1, 64, kO2); STG(gAst, As1, 192, kO2);
        SBAR(); LGKM0();
        PRIO1(); MM(1, 0); PRIO0();
        VMC6();   // next even tile fully landed (through P5's stage)
        SBAR();
    }

    // ---- fused epilogue: resid = pred - w*R, accumulate resid^2 ----
    // C/D frag layout: col = l16, row = q*4 + r (m89/m91 convention).
    float lsum = 0.0f;
    #pragma unroll
    for (int m8 = 0; m8 < 8; m8++) {
        #pragma unroll
        for (int r = 0; r < 4; r++) {
            const int grow = row0 + wm * 128 + m8 * 16 + q * 4 + r;
            const float wv = W[grow];
            const float* Rr = R + (size_t)grow * I_DIM + col0 + wn * 32 + l16;
            #pragma unroll
            for (int n4 = 0; n4 < 4; n4++) {
                const int coff = (n4 >> 1) * 128 + (n4 & 1) * 16;
                const float resid = acc[m8][n4][r] - wv * Rr[coff];
                lsum += resid * resid;
            }
        }
    }

    #pragma unroll
    for (int off = 32; off > 0; off >>= 1)
        lsum += __shfl_down(lsum, off);

    // reuse As as reduction scratch; __syncthreads drains vmcnt (tail stages)
    __syncthreads();
    float* wsum = (float*)As0;
    if (lane == 0) wsum[wave] = lsum;
    __syncthreads();
    if (tid == 0) {
        float bs = 0.f;
        #pragma unroll
        for (int wvi = 0; wvi < 8; wvi++) bs += wsum[wvi];
        atomicAdd(out, bs * (1.0f / ((float)U_DIM * (float)I_DIM)));
    }
}

// ---- fallback: proven V1 fused kernel (no workspace) ----
#define FBM 128
#define FBN 128
#define FBK 32
#define LDA 40
#define LDB 40

__global__ __launch_bounds__(256) void fused_loss_kernel(
    const float* __restrict__ R, const float* __restrict__ S,
    const float* __restrict__ W, float* __restrict__ out)
{
    __shared__ unsigned short Asf[FBM * LDA];
    __shared__ unsigned short Bsf[FBN * LDB];
    __shared__ float wavesum[4];

    const int tid  = threadIdx.x;
    const int lane = tid & 63;
    const int wave = tid >> 6;
    const int wm   = wave >> 1;
    const int wn   = wave & 1;
    const int q    = lane >> 4;
    const int l16  = lane & 15;

    const int bid = blockIdx.x;
    const int sq  = bid >> 6;
    const int w64 = bid & 63;
    const int br  = (sq >> 3) * 8 + (w64 >> 3);
    const int bc  = (sq & 7) * 8 + (w64 & 7);
    const int row0 = br * FBM;
    const int col0 = bc * FBN;

    const int ra = tid >> 2;
    const int ca = (tid & 3) * 8;
    const float* gA = R + (size_t)(row0 + ra) * (size_t)K_DIM + ca;

    const int kb2 = (tid & 15) * 2;
    const int nb  = (tid >> 4) * 8;
    const float* gB = S + (size_t)kb2 * (size_t)I_DIM + col0 + nb;

    f32x4 acc[4][4];
    #pragma unroll
    for (int i = 0; i < 4; i++)
        #pragma unroll
        for (int j = 0; j < 4; j++)
            acc[i][j] = (f32x4){0.f, 0.f, 0.f, 0.f};

    for (int k0 = 0; k0 < K_DIM; k0 += FBK) {
        const float4 a0 = *(const float4*)(gA);
        const float4 a1 = *(const float4*)(gA + 4);
        const float4 a2 = *(const float4*)(gA + (size_t)64 * K_DIM);
        const float4 a3 = *(const float4*)(gA + (size_t)64 * K_DIM + 4);
        const float4 b0 = *(const float4*)(gB);
        const float4 b1 = *(const float4*)(gB + 4);
        const float4 b2 = *(const float4*)(gB + I_DIM);
        const float4 b3 = *(const float4*)(gB + I_DIM + 4);
        gA += FBK;
        gB += (size_t)FBK * I_DIM;

        __syncthreads();

        uint4 wa0; wa0.x = pk2(a0.x, a0.y); wa0.y = pk2(a0.z, a0.w);
                   wa0.z = pk2(a1.x, a1.y); wa0.w = pk2(a1.z, a1.w);
        *(uint4*)&Asf[ra * LDA + ca] = wa0;
        uint4 wa1; wa1.x = pk2(a2.x, a2.y); wa1.y = pk2(a2.z, a2.w);
                   wa1.z = pk2(a3.x, a3.y); wa1.w = pk2(a3.z, a3.w);
        *(uint4*)&Asf[(ra + 64) * LDA + ca] = wa1;

        float r0[8] = {b0.x, b0.y, b0.z, b0.w, b1.x, b1.y, b1.z, b1.w};
        float r1[8] = {b2.x, b2.y, b2.z, b2.w, b3.x, b3.y, b3.z, b3.w};
        #pragma unroll
        for (int e = 0; e < 8; e++) {
            *(unsigned int*)&Bsf[(nb + e) * LDB + kb2] = pk2(r0[e], r1[e]);
        }
        __syncthreads();

        bf16x8 af[4], bfv[4];
        #pragma unroll
        for (int i = 0; i < 4; i++)
            af[i] = *(const bf16x8*)&Asf[(wm * 64 + i * 16 + l16) * LDA + q * 8];
        #pragma unroll
        for (int j = 0; j < 4; j++)
            bfv[j] = *(const bf16x8*)&Bsf[(wn * 64 + j * 16 + l16) * LDB + q * 8];
        #pragma unroll
        for (int i = 0; i < 4; i++)
            #pragma unroll
            for (int j = 0; j < 4; j++)
                acc[i][j] = __builtin_amdgcn_mfma_f32_16x16x32_bf16(
                    af[i], bfv[j], acc[i][j], 0, 0, 0);
    }

    float lsum = 0.0f;
    #pragma unroll
    for (int i = 0; i < 4; i++) {
        #pragma unroll
        for (int r = 0; r < 4; r++) {
            const int grow = row0 + wm * 64 + i * 16 + q * 4 + r;
            const float wv = W[grow];
            const float* Rrow = R + (size_t)grow * I_DIM + col0 + wn * 64 + l16;
            #pragma unroll
            for (int j = 0; j < 4; j++) {
                const float resid = acc[i][j][r] - wv * Rrow[j * 16];
                lsum += resid * resid;
            }
        }
    }

    #pragma unroll
    for (int off = 32; off > 0; off >>= 1)
        lsum += __shfl_down(lsum, off);
    if (lane == 0) wavesum[wave] = lsum;
    __syncthreads();
    if (tid == 0) {
        const float bs = wavesum[0] + wavesum[1] + wavesum[2] + wavesum[3];
        atomicAdd(out, bs * (1.0f / ((float)U_DIM * (float)I_DIM)));
    }
}

extern "C" void kernel_launch(void* const* d_in, const int* in_sizes, int n_in,
                              void* d_out, int out_size, void* d_ws, size_t ws_size,
                              hipStream_t stream) {
    const float* R = (const float*)d_in[0];
    const float* S = (const float*)d_in[1];
    const float* W = (const float*)d_in[2];
    float* out = (float*)d_out;

    zero_out_kernel<<<dim3(1), dim3(1), 0, stream>>>(out);

    const size_t need = (size_t)U_DIM * K_DIM * 2 + (size_t)I_DIM * K_DIM * 2; // 256MB
    if (ws_size >= need) {
        unsigned short* Rb  = (unsigned short*)d_ws;
        unsigned short* STb = Rb + (size_t)U_DIM * K_DIM;
        convR_kernel<<<dim3(U_DIM * K_DIM / 8 / 256), dim3(256), 0, stream>>>(R, Rb);
        convS_kernel<<<dim3((K_DIM / 64) * (I_DIM / 64)), dim3(256), 0, stream>>>(S, STb);
        gemm_loss_kernel<<<dim3(1024), dim3(512), 0, stream>>>(Rb, STb, R, W, out);
    } else {
        fused_loss_kernel<<<dim3((U_DIM / FBM) * (I_DIM / FBN)), dim3(256), 0, stream>>>(
            R, S, W, out);
    }
}